// Round 9
// baseline (15612.898 us; speedup 1.0000x reference)
//
#include <hip/hip_runtime.h>
#include <math.h>

#define NTH 256
#define XW 28      // X row width ([c][v] layout, cols 25..27 pad)
#define CP 68      // T row width ([v][c] layout, cols 64..67 pad)
#define NV 28

__device__ __forceinline__ float tanh_fast(float x) {
    float t = fminf(fmaxf(2.0f * x, -30.0f), 30.0f);
    float e = __expf(t);
    return (e - 1.0f) / (e + 1.0f);
}

// T[v][o] = sum_u X[o][u] * As[v][u]  for v in this thread's strip (one row o)
__device__ __forceinline__ void amul(const float* __restrict__ X, float* __restrict__ T,
                                     const float* __restrict__ As, int o, int vs)
{
    float a[7];
    #pragma unroll
    for (int j = 0; j < 7; ++j) a[j] = 0.f;
    const float* xp = X + o * XW;
    #pragma unroll
    for (int ub = 0; ub < 7; ++ub) {
        float4 x = *(const float4*)(xp + 4 * ub);
        #pragma unroll
        for (int j = 0; j < 7; ++j) {
            float4 aa = *(const float4*)(As + (vs + 4 * j) * XW + 4 * ub);
            a[j] = fmaf(x.x, aa.x, fmaf(x.y, aa.y, fmaf(x.z, aa.z, fmaf(x.w, aa.w, a[j]))));
        }
    }
    #pragma unroll
    for (int j = 0; j < 7; ++j) T[(vs + 4 * j) * CP + o] = a[j];
}

// acc = W[o][:] . T[v][:] + b ; TOX=true -> X[o][v]=tanh ; TOX=false -> Tout[v][o]=tanh
template<bool TOX>
__device__ __forceinline__ void wmul(const float* __restrict__ T, float* __restrict__ outp,
                                     const float* __restrict__ Wg, float b, int o, int vs)
{
    float a[7];
    #pragma unroll
    for (int j = 0; j < 7; ++j) a[j] = b;
    const float* wp = Wg + o * 64;
    #pragma unroll
    for (int cb = 0; cb < 16; ++cb) {
        float4 w = *(const float4*)(wp + 4 * cb);
        #pragma unroll
        for (int j = 0; j < 7; ++j) {
            float4 t = *(const float4*)(T + (vs + 4 * j) * CP + 4 * cb);
            a[j] = fmaf(w.x, t.x, fmaf(w.y, t.y, fmaf(w.z, t.z, fmaf(w.w, t.w, a[j]))));
        }
    }
    #pragma unroll
    for (int j = 0; j < 7; ++j) {
        int v = vs + 4 * j;
        if (TOX) outp[o * XW + v] = tanh_fast(a[j]);
        else     outp[v * CP + o] = tanh_fast(a[j]);
    }
}

// First 3 layers of f: X -> (A,W1,tanh) -> (A,W2,tanh) -> (A,W3,tanh) -> Tb[v][c].
__device__ __forceinline__ void ode_head(float* X, float* Ta, float* Tb, const float* As,
    const float* W1, float b1r, const float* W2, float b2r, const float* W3, float b3r,
    int o, int vs)
{
    amul(X, Ta, As, o, vs);
    __syncthreads();
    wmul<true>(Ta, X, W1, b1r, o, vs);
    amul(X, Tb, As, o, vs);
    __syncthreads();
    wmul<true>(Tb, X, W2, b2r, o, vs);
    amul(X, Ta, As, o, vs);
    __syncthreads();
    wmul<false>(Ta, Tb, W3, b3r, o, vs);
    __syncthreads();
}

// Final layer (W4, no tanh): K[j] = W4[o][:] . Tb[v][:] + b4. Macro in kernel scope.
#define WMUL_K(K) do {                                                                 \
    _Pragma("unroll")                                                                  \
    for (int j = 0; j < 7; ++j) K[j] = b4r;                                            \
    _Pragma("unroll")                                                                  \
    for (int cb = 0; cb < 16; ++cb) {                                                  \
        float4 w = *(const float4*)(W4 + o * 64 + 4 * cb);                             \
        _Pragma("unroll")                                                              \
        for (int j = 0; j < 7; ++j) {                                                  \
            float4 t = *(const float4*)(Tb + (vs + 4 * j) * CP + 4 * cb);              \
            K[j] = fmaf(w.x, t.x, fmaf(w.y, t.y, fmaf(w.z, t.z, fmaf(w.w, t.w, K[j]))));\
        }                                                                              \
    }                                                                                  \
} while (0)

// blocks 0..511: scan (b = blk, 32 sequential steps, y carried in registers)
// blocks 512..16895: z_hat (one step per (b,t))
// waves_per_eu pinned to (4,4): at 256 thr (4 waves/block) this targets exactly
// 4 blocks/CU -> VGPR budget 128. Without the pin, the occupancy heuristic
// targeted 8 waves/EU, clamped VGPRs to 64 (observed), and spilled ~20 floats
// per thread -> 8.5 GB scratch writes + L2 thrash -> 31.5 GB W-read HBM misses.
__global__ void __launch_bounds__(NTH)
__attribute__((amdgpu_waves_per_eu(4, 4)))
rk4_both(const float* __restrict__ z, float* __restrict__ out,
         const float* __restrict__ Ag, const float* __restrict__ pe,
         const float* __restrict__ W1, const float* __restrict__ B1,
         const float* __restrict__ W2, const float* __restrict__ B2,
         const float* __restrict__ W3, const float* __restrict__ B3,
         const float* __restrict__ W4, const float* __restrict__ B4)
{
    __shared__ float X[64 * XW];
    __shared__ float Ta[NV * CP];
    __shared__ float Tb[NV * CP];
    __shared__ float As[NV * XW];

    int tid = threadIdx.x;
    int o = tid >> 2, vs = tid & 3;   // one channel row per thread

    int blk = blockIdx.x;
    bool scan = (blk < 512);
    int b, t_src, nsteps;
    if (scan) { b = blk; t_src = 31; nsteps = 32; }
    else      { int q = blk - 512; b = q >> 5; t_src = q & 31; nsteps = 1; }

    // stage A (zero pads, then fill)
    for (int i = tid; i < NV * XW; i += NTH) As[i] = 0.f;
    __syncthreads();
    for (int i = tid; i < 25 * 25; i += NTH) { int v = i / 25, u = i - v * 25; As[v * XW + u] = Ag[i]; }
    __syncthreads();

    float b1r = B1[o], b2r = B2[o], b3r = B3[o], b4r = B4[o];

    // load y into registers (pad strips -> 0)
    const float* zb = z + (size_t)b * 64 * 64 * 25;
    float* outb = out + (size_t)b * 64 * 64 * 25;
    float y[7];
    #pragma unroll
    for (int j = 0; j < 7; ++j) {
        int v = vs + 4 * j;
        y[j] = (v < 25) ? zb[((size_t)o * 64 + t_src) * 25 + v] : 0.f;
    }

    for (int s = 0; s < nsteps; ++s) {
        int pr = scan ? s : 0;
        float pe0 = pe[pr * 64 + o];
        float pe1 = pe[(pr + 1) * 64 + o];

        float kS[7], kT[7], kU[7];

        // X1 = y + pe0
        #pragma unroll
        for (int j = 0; j < 7; ++j) X[o * XW + vs + 4 * j] = y[j] + pe0;
        ode_head(X, Ta, Tb, As, W1, b1r, W2, b2r, W3, b3r, o, vs);
        WMUL_K(kS);                         // kS = k1

        // X2 = y + k1/3 + pe0
        #pragma unroll
        for (int j = 0; j < 7; ++j) X[o * XW + vs + 4 * j] = y[j] + kS[j] * (1.f / 3.f) + pe0;
        ode_head(X, Ta, Tb, As, W1, b1r, W2, b2r, W3, b3r, o, vs);
        WMUL_K(kT);                         // kT = k2

        // X3 = y - k1/3 + k2 + pe0
        #pragma unroll
        for (int j = 0; j < 7; ++j) X[o * XW + vs + 4 * j] = y[j] - kS[j] * (1.f / 3.f) + kT[j] + pe0;
        ode_head(X, Ta, Tb, As, W1, b1r, W2, b2r, W3, b3r, o, vs);
        WMUL_K(kU);                         // kU = k3

        // X4 = y + k1 - k2 + k3 + pe1 ; fold S = k1 + 3(k2+k3) into kS
        #pragma unroll
        for (int j = 0; j < 7; ++j) {
            X[o * XW + vs + 4 * j] = y[j] + kS[j] - kT[j] + kU[j] + pe1;
            kS[j] = kS[j] + 3.f * (kT[j] + kU[j]);
        }
        ode_head(X, Ta, Tb, As, W1, b1r, W2, b2r, W3, b3r, o, vs);
        WMUL_K(kT);                         // kT = k4

        // y' = y + (S + k4)/8 ; store
        int t_dst = scan ? (32 + s) : t_src;
        #pragma unroll
        for (int j = 0; j < 7; ++j) {
            int v = vs + 4 * j;
            float n = y[j] + (kS[j] + kT[j]) * 0.125f;
            y[j] = n;
            if (v < 25) outb[((size_t)o * 64 + t_dst) * 25 + v] = n;
        }
    }
}

__global__ void pe_kernel(float* __restrict__ pe) {
    int idx = blockIdx.x * blockDim.x + threadIdx.x;
    if (idx >= 64 * 64) return;
    int t = idx >> 6, c = idx & 63;
    int i2 = c & ~1;
    float div = expf((float)i2 * (-logf(10000.0f) / 64.0f));
    float arg = (float)t * div;
    pe[idx] = (c & 1) ? cosf(arg) : sinf(arg);
}

extern "C" void kernel_launch(void* const* d_in, const int* in_sizes, int n_in,
                              void* d_out, int out_size, void* d_ws, size_t ws_size,
                              hipStream_t stream) {
    const float* z  = (const float*)d_in[0];
    const float* A  = (const float*)d_in[1];
    const float* w1 = (const float*)d_in[2];
    const float* b1 = (const float*)d_in[3];
    const float* w2 = (const float*)d_in[4];
    const float* b2 = (const float*)d_in[5];
    const float* w3 = (const float*)d_in[6];
    const float* b3 = (const float*)d_in[7];
    const float* w4 = (const float*)d_in[8];
    const float* b4 = (const float*)d_in[9];
    float* out = (float*)d_out;
    float* pe  = (float*)d_ws;   // 64*64 floats

    pe_kernel<<<16, 256, 0, stream>>>(pe);

    // one fused dispatch: blocks 0..511 = autoregressive scan (long critical
    // path, dispatched first); blocks 512..16895 = z_hat throughput work
    rk4_both<<<512 + 512 * 32, NTH, 0, stream>>>(
        z, out, A, pe, w1, b1, w2, b2, w3, b3, w4, b4);
}